// Round 4
// baseline (960.722 us; speedup 1.0000x reference)
//
#include <hip/hip_runtime.h>
#include <hip/hip_bf16.h>
#include <stdint.h>

#define D_MODEL 1024
#define NHEAD   16
#define HDIM    64
#define BATCH   2
#define SEQ     2048
#define BS_TOK  (BATCH*SEQ)   // 4096 tokens

using bf16 = __hip_bfloat16;
typedef __attribute__((ext_vector_type(8))) short frag8;   // 8 bf16 = 4 VGPRs (A/B operand)
typedef __attribute__((ext_vector_type(4))) float facc4;   // 4 fp32 accumulator

// ---------------------------------------------------------------- async 16B global->LDS
__device__ __forceinline__ void gld_lds16(const void* g, void* l) {
    __builtin_amdgcn_global_load_lds(
        reinterpret_cast<const __attribute__((address_space(1))) uint32_t*>(
            reinterpret_cast<uintptr_t>(g)),
        reinterpret_cast<__attribute__((address_space(3))) uint32_t*>(
            reinterpret_cast<uintptr_t>(l)),
        16, 0, 0);
}

// LDS-only barrier: orders ds_write->ds_read across waves WITHOUT draining vmcnt,
// so outstanding global stores/loads stay in flight across chunk boundaries (T4).
__device__ __forceinline__ void ldsbar() {
    asm volatile("s_waitcnt lgkmcnt(0)" ::: "memory");
    __builtin_amdgcn_sched_barrier(0);   // rule #18: pin nothing crosses the wait
    __builtin_amdgcn_s_barrier();
}

// ---------------------------------------------------------------- cvt fp32->bf16: all 7 tensors, one launch
__global__ __launch_bounds__(256) void cvt_all(const float* __restrict__ q, const float* __restrict__ k,
                                               const float* __restrict__ v, const float* __restrict__ wq,
                                               const float* __restrict__ wk, const float* __restrict__ wv,
                                               const float* __restrict__ wo,
                                               ushort* __restrict__ dq, ushort* __restrict__ dk,
                                               ushort* __restrict__ dv, ushort* __restrict__ dwq,
                                               ushort* __restrict__ dwk, ushort* __restrict__ dwv,
                                               ushort* __restrict__ dwo,
                                               int nbt, int n4t, int nbw, int n4w) {
    int blk = blockIdx.x;
    const float4* s; ushort4* d; int i, n4;
    if (blk < 3 * nbt) {
        int t = blk / nbt;
        i = (blk - t * nbt) * 256 + threadIdx.x; n4 = n4t;
        s = (const float4*)(t == 0 ? q : t == 1 ? k : v);
        d = (ushort4*)(t == 0 ? dq : t == 1 ? dk : dv);
    } else {
        blk -= 3 * nbt;
        int t = blk / nbw;
        i = (blk - t * nbw) * 256 + threadIdx.x; n4 = n4w;
        s = (const float4*)(t == 0 ? wq : t == 1 ? wk : t == 2 ? wv : wo);
        d = (ushort4*)(t == 0 ? dwq : t == 1 ? dwk : t == 2 ? dwv : dwo);
    }
    if (i >= n4) return;
    float4 vv = s[i];
    bf16 a = __float2bfloat16(vv.x), b = __float2bfloat16(vv.y),
         c = __float2bfloat16(vv.z), e = __float2bfloat16(vv.w);
    ushort4 u;
    __builtin_memcpy(&u.x, &a, 2);
    __builtin_memcpy(&u.y, &b, 2);
    __builtin_memcpy(&u.z, &c, 2);
    __builtin_memcpy(&u.w, &e, 2);
    d[i] = u;
}

// ---------------------------------------------------------------- GEMM core: C = A(MxK)*Bt(NxK)^T + bias
// 128x64 tile / 256 threads (4 waves 2x2), BK=64, 2-phase LDS double-buffer,
// global_load_lds width-16 with PRE-SWIZZLED global source (both-sides rule):
// stored[row][c8] = global[row][c8 ^ (row&7)], reads XOR the same way.
// C/D layout (verified gfx950): col = lane&15, row = (lane>>4)*4 + reg.
template<bool OUT_BF16, bool ROW_BIAS>
__device__ __forceinline__ void gemm_core(bf16* AsBuf, bf16* BsBuf,
                                          const bf16* __restrict__ A,
                                          const bf16* __restrict__ Bt,
                                          const float* __restrict__ bias,
                                          void* __restrict__ Cout,
                                          int M, int N, int K, int bx, int by) {
    const int tid  = threadIdx.x;
    const int lane = tid & 63, wave = tid >> 6;
    const int wm = wave >> 1, wn = wave & 1;
    const int L15 = lane & 15, quad = lane >> 4;
    const int m0 = by * 128, n0 = bx * 64;
    const int ar  = tid >> 3;                       // 0..31: row-sub within a 32-row group
    const int acS = ((tid & 7) ^ (ar & 7)) * 8;     // pre-swizzled k-chunk (elems)

    const bf16* Agl[4];
    const bf16* Bgl[2];
#pragma unroll
    for (int q = 0; q < 4; q++) Agl[q] = A + (size_t)(m0 + q * 32 + ar) * K + acS;
#pragma unroll
    for (int q = 0; q < 2; q++) Bgl[q] = Bt + (size_t)(n0 + q * 32 + ar) * K + acS;

    const facc4 zero4 = {0.f, 0.f, 0.f, 0.f};
    facc4 acc[4][2];
#pragma unroll
    for (int mt = 0; mt < 4; mt++) { acc[mt][0] = zero4; acc[mt][1] = zero4; }

#define G_STAGE(BUF, KO) do {                                                   \
        _Pragma("unroll")                                                       \
        for (int q = 0; q < 4; q++)                                             \
            gld_lds16(Agl[q] + (KO), AsBuf + (BUF) * 8192 + q * 2048 + wave * 512); \
        _Pragma("unroll")                                                       \
        for (int q = 0; q < 2; q++)                                             \
            gld_lds16(Bgl[q] + (KO), BsBuf + (BUF) * 4096 + q * 2048 + wave * 512); \
    } while (0)

#define G_COMPUTE(BUF) do {                                                     \
        const bf16* Ab = AsBuf + (BUF) * 8192;                                  \
        const bf16* Bb = BsBuf + (BUF) * 4096;                                  \
        _Pragma("unroll")                                                       \
        for (int h = 0; h < 2; h++) {                                           \
            frag8 af[4], bfr[2];                                                \
            _Pragma("unroll")                                                   \
            for (int mt = 0; mt < 4; mt++) {                                    \
                int row = wm * 64 + mt * 16 + L15;                              \
                int c8 = (h * 4 + quad) ^ (row & 7);                            \
                af[mt] = *(const frag8*)(Ab + row * 64 + c8 * 8);               \
            }                                                                   \
            _Pragma("unroll")                                                   \
            for (int nt = 0; nt < 2; nt++) {                                    \
                int row = wn * 32 + nt * 16 + L15;                              \
                int c8 = (h * 4 + quad) ^ (row & 7);                            \
                bfr[nt] = *(const frag8*)(Bb + row * 64 + c8 * 8);              \
            }                                                                   \
            _Pragma("unroll")                                                   \
            for (int mt = 0; mt < 4; mt++)                                      \
                _Pragma("unroll")                                               \
                for (int nt = 0; nt < 2; nt++)                                  \
                    acc[mt][nt] = __builtin_amdgcn_mfma_f32_16x16x32_bf16(af[mt], bfr[nt], acc[mt][nt], 0, 0, 0); \
        }                                                                       \
    } while (0)

    G_STAGE(0, 0);
    __syncthreads();
    int cur = 0;
    for (int k0 = 64; k0 < K; k0 += 64) {
        G_STAGE(cur ^ 1, k0);    // next tile's loads issue under current compute
        G_COMPUTE(cur);
        __syncthreads();         // drains next-stage + fences LDS reuse
        cur ^= 1;
    }
    G_COMPUTE(cur);

#pragma unroll
    for (int mt = 0; mt < 4; mt++)
#pragma unroll
        for (int nt = 0; nt < 2; nt++)
#pragma unroll
            for (int r = 0; r < 4; r++) {
                int row = m0 + wm * 64 + mt * 16 + quad * 4 + r;
                int col = n0 + wn * 32 + nt * 16 + L15;
                float v = acc[mt][nt][r] + (ROW_BIAS ? bias[row] : bias[col]);
                if (OUT_BF16) ((bf16*)Cout)[(size_t)row * N + col] = __float2bfloat16(v);
                else          ((float*)Cout)[(size_t)row * N + col] = v;
            }
#undef G_STAGE
#undef G_COMPUTE
}

// All three projection GEMMs in ONE launch: 1536 blocks = 6/CU, so independent
// blocks overlap each other's stage drains (was 2-4/CU in separate launches).
__global__ __launch_bounds__(256) void proj_all(const bf16* __restrict__ qA, const bf16* __restrict__ Wq,
                                                const float* __restrict__ bq, bf16* __restrict__ qO,
                                                const bf16* __restrict__ kA, const bf16* __restrict__ Wk,
                                                const float* __restrict__ bk, bf16* __restrict__ kO,
                                                const bf16* __restrict__ Wv, const bf16* __restrict__ vA,
                                                const float* __restrict__ bv, bf16* __restrict__ vO) {
    __shared__ bf16 As[2 * 8192];   // 32 KB
    __shared__ bf16 Bs[2 * 4096];   // 16 KB
    int id = blockIdx.x;
    if (id < 512) {
        gemm_core<true, false>(As, Bs, qA, Wq, bq, qO, BS_TOK, D_MODEL, D_MODEL, id & 15, id >> 4);
    } else if (id < 1024) {
        id -= 512;
        gemm_core<true, false>(As, Bs, kA, Wk, bk, kO, BS_TOK, D_MODEL, D_MODEL, id & 15, id >> 4);
    } else {
        id -= 1024;   // vT = Wv @ v^T (role-swapped, row bias): grid (64, 8)
        gemm_core<true, true>(As, Bs, Wv, vA, bv, vO, D_MODEL, BS_TOK, D_MODEL, id & 63, id >> 6);
    }
}

template<bool OUT_BF16, bool ROW_BIAS>
__global__ __launch_bounds__(256) void gemm_bt(const bf16* __restrict__ A,
                                               const bf16* __restrict__ Bt,
                                               const float* __restrict__ bias,
                                               void* __restrict__ Cout,
                                               int M, int N, int K) {
    __shared__ bf16 As[2 * 8192];
    __shared__ bf16 Bs[2 * 4096];
    gemm_core<OUT_BF16, ROW_BIAS>(As, Bs, A, Bt, bias, Cout, M, N, K, blockIdx.x, blockIdx.y);
}

// ---------------------------------------------------------------- attention
// One block per (b, h, 16-row Q strip). 4 waves. Two-pass online softmax:
//   pass 1: QK^T + exp -> row sums (unrolled x2 for MFMA ILP).
//   pass 2: 4 chunks of 512 keys, DOUBLE-BUFFERED ptile: STAGE(c+1) (QK^T,
//           exp, normalized attn stores straight from regs via L2, bf16 P ->
//           LDS) overlaps PV(c) (MFMA from ptile + vT). ONE lgkm-only barrier
//           per chunk; global stores never drain inside the loop.
// T1 XCD-chunked block swizzle keeps each (b,h)'s K/V slice in one XCD L2.
__device__ __forceinline__ int pidx2(int row, int col) {
    int chunk = col >> 3;
    return row * 512 + (((chunk ^ (row & 7)) << 3) | (col & 7));
}

__global__ __launch_bounds__(256) void attn_kernel(const bf16* __restrict__ qp,
                                                   const bf16* __restrict__ kp,
                                                   const bf16* __restrict__ vT,
                                                   bf16* __restrict__ zbuf,
                                                   float* __restrict__ attn_out) {
    __shared__ bf16 ptile[2][16 * 512];   // 2 x 16 KB swizzled P chunks
    __shared__ float sred[4][16];
    __shared__ float sinv[16];
    const int bid0 = blockIdx.x;
    const int bid = (bid0 & 7) * 512 + (bid0 >> 3);   // bijective XCD chunking (4096 = 8*512)
    const int strip = bid & 127, bh = bid >> 7;
    const int b = bh >> 4, h = bh & 15;
    const int i0 = strip * 16;
    const int tid = threadIdx.x, lane = tid & 63, wave = tid >> 6;
    const int L15 = lane & 15, quad = lane >> 4;
    const float scale = 0.125f;  // 1/sqrt(64)

    // Q fragments: A[m=lane&15][k=quad*8+j], two k-steps of 32
    frag8 aq0, aq1;
    {
        size_t base = (size_t)(b * SEQ + i0 + L15) * D_MODEL + h * HDIM + quad * 8;
        aq0 = *(const frag8*)(qp + base);
        aq1 = *(const frag8*)(qp + base + 32);
    }
    const facc4 zero4 = {0.f, 0.f, 0.f, 0.f};

    // ---- pass 1: row sums of exp(scores); |s| small: no max-subtraction needed
    float sums[4] = {0.f, 0.f, 0.f, 0.f};
    for (int tt = 0; tt < 32; tt += 2) {
        int j0a = wave * 512 + tt * 16;
        size_t kba = (size_t)(b * SEQ + j0a + L15) * D_MODEL + h * HDIM + quad * 8;
        frag8 a0 = *(const frag8*)(kp + kba);
        frag8 a1 = *(const frag8*)(kp + kba + 32);
        frag8 c0 = *(const frag8*)(kp + kba + (size_t)16 * D_MODEL);
        frag8 c1 = *(const frag8*)(kp + kba + (size_t)16 * D_MODEL + 32);
        facc4 acca = zero4, accb = zero4;
        acca = __builtin_amdgcn_mfma_f32_16x16x32_bf16(aq0, a0, acca, 0, 0, 0);
        accb = __builtin_amdgcn_mfma_f32_16x16x32_bf16(aq0, c0, accb, 0, 0, 0);
        acca = __builtin_amdgcn_mfma_f32_16x16x32_bf16(aq1, a1, acca, 0, 0, 0);
        accb = __builtin_amdgcn_mfma_f32_16x16x32_bf16(aq1, c1, accb, 0, 0, 0);
#pragma unroll
        for (int r = 0; r < 4; r++)
            sums[r] += __expf(acca[r] * scale) + __expf(accb[r] * scale);
    }
#pragma unroll
    for (int m = 1; m <= 8; m <<= 1)
#pragma unroll
        for (int r = 0; r < 4; r++) sums[r] += __shfl_xor(sums[r], m, 64);
    if (L15 == 0) {
#pragma unroll
        for (int r = 0; r < 4; r++) sred[wave][quad * 4 + r] = sums[r];
    }
    __syncthreads();
    if (tid < 16) sinv[tid] = 1.0f / (sred[0][tid] + sred[1][tid] + sred[2][tid] + sred[3][tid]);
    __syncthreads();

    float invr[4];
#pragma unroll
    for (int r = 0; r < 4; r++) invr[r] = sinv[quad * 4 + r];

    // ---- pass 2: double-buffered chunk pipeline
    facc4 zacc = zero4;
    const bf16* vrow = vT + (size_t)(h * HDIM + wave * 16 + L15) * BS_TOK + b * SEQ;
    const size_t obase = ((size_t)bh * SEQ + i0) * SEQ;

// QK^T + exp for chunk CHK; writes normalized attn (plain stores -> L2
// write-combines the 64B segments into full lines) + bf16 P into ptile[BUF].
#define ATT_STAGE(CHK, BUF) do {                                                     \
        _Pragma("unroll")                                                            \
        for (int tt = 0; tt < 8; tt++) {                                             \
            int jrel = wave * 128 + tt * 16;                                         \
            int j0 = (CHK) * 512 + jrel;                                             \
            size_t kb = (size_t)(b * SEQ + j0 + L15) * D_MODEL + h * HDIM + quad * 8;\
            frag8 kf0 = *(const frag8*)(kp + kb);                                    \
            frag8 kf1 = *(const frag8*)(kp + kb + 32);                               \
            facc4 acc = zero4;                                                       \
            acc = __builtin_amdgcn_mfma_f32_16x16x32_bf16(aq0, kf0, acc, 0, 0, 0);   \
            acc = __builtin_amdgcn_mfma_f32_16x16x32_bf16(aq1, kf1, acc, 0, 0, 0);   \
            int colw = jrel + L15;                                                   \
            _Pragma("unroll")                                                        \
            for (int r = 0; r < 4; r++) {                                            \
                int row = quad * 4 + r;                                              \
                float a = __expf(acc[r] * scale) * invr[r];                          \
                attn_out[obase + (size_t)row * SEQ + j0 + L15] = a;                  \
                ptile[BUF][pidx2(row, colw)] = __float2bfloat16(a);                  \
            }                                                                        \
        }                                                                            \
    } while (0)

// PV over chunk CHK from ptile[BUF]: A = P[q=L15][k], B = vT[d=wave*16+L15][k]
#define ATT_PV(CHK, BUF) do {                                                        \
        _Pragma("unroll")                                                            \
        for (int k0 = 0; k0 < 512; k0 += 32) {                                       \
            frag8 pa = *(const frag8*)&ptile[BUF][L15 * 512 +                        \
                        ((((k0 >> 3) + quad) ^ (L15 & 7)) << 3)];                    \
            frag8 vb = *(const frag8*)(vrow + (CHK) * 512 + k0 + quad * 8);          \
            zacc = __builtin_amdgcn_mfma_f32_16x16x32_bf16(pa, vb, zacc, 0, 0, 0);   \
        }                                                                            \
    } while (0)

    ATT_STAGE(0, 0);
    ldsbar();
    ATT_STAGE(1, 1); ATT_PV(0, 0);
    ldsbar();
    ATT_STAGE(2, 0); ATT_PV(1, 1);
    ldsbar();
    ATT_STAGE(3, 1); ATT_PV(2, 0);
    ldsbar();
    ATT_PV(3, 1);
#undef ATT_STAGE
#undef ATT_PV

    // z write: z[q=quad*4+r][d=wave*16+L15], already normalized (P was normalized)
#pragma unroll
    for (int r = 0; r < 4; r++) {
        size_t row = (size_t)(b * SEQ + i0 + quad * 4 + r);
        zbuf[row * D_MODEL + h * HDIM + wave * 16 + L15] = __float2bfloat16(zacc[r]);
    }
}

// ---------------------------------------------------------------- launch
extern "C" void kernel_launch(void* const* d_in, const int* in_sizes, int n_in,
                              void* d_out, int out_size, void* d_ws, size_t ws_size,
                              hipStream_t stream) {
    const float* q   = (const float*)d_in[0];
    const float* k   = (const float*)d_in[1];
    const float* v   = (const float*)d_in[2];
    const float* w_q = (const float*)d_in[3];
    const float* b_q = (const float*)d_in[4];
    const float* w_k = (const float*)d_in[5];
    const float* b_k = (const float*)d_in[6];
    const float* w_v = (const float*)d_in[7];
    const float* b_v = (const float*)d_in[8];
    const float* w_o = (const float*)d_in[9];
    const float* b_o = (const float*)d_in[10];

    char* ws = (char*)d_ws;
    const size_t TOK = (size_t)BS_TOK * D_MODEL;      // 4.19M elems
    const size_t WM  = (size_t)D_MODEL * D_MODEL;     // 1.05M elems
    bf16* qbf  = (bf16*)(ws);                          // 8 MB
    bf16* kbf  = (bf16*)(ws + 8388608);
    bf16* vbf  = (bf16*)(ws + 16777216);
    bf16* wqb  = (bf16*)(ws + 25165824);               // 2 MB each
    bf16* wkb  = (bf16*)(ws + 27262976);
    bf16* wvb  = (bf16*)(ws + 29360128);
    bf16* wob  = (bf16*)(ws + 31457280);
    bf16* qp   = (bf16*)(ws + 33554432);               // 8 MB
    bf16* kp   = (bf16*)(ws + 41943040);
    bf16* vT   = (bf16*)(ws + 50331648);               // V^T per feature row
    bf16* zbf  = (bf16*)(ws + 58720256);

    float* z_out    = (float*)d_out;
    float* attn_out = (float*)d_out + (size_t)BATCH * SEQ * D_MODEL;  // +4194304

    // fp32 -> bf16: all 7 tensors, one launch
    int n4t = (int)(TOK / 4), n4w = (int)(WM / 4);
    int nbt = (n4t + 255) / 256, nbw = (n4w + 255) / 256;
    cvt_all<<<3 * nbt + 4 * nbw, 256, 0, stream>>>(q, k, v, w_q, w_k, w_v, w_o,
                                                   (ushort*)qbf, (ushort*)kbf, (ushort*)vbf,
                                                   (ushort*)wqb, (ushort*)wkb, (ushort*)wvb,
                                                   (ushort*)wob, nbt, n4t, nbw, n4w);

    // all three projections in one launch (Q, K, and role-swapped V^T)
    proj_all<<<1536, 256, 0, stream>>>(qbf, wqb, b_q, qp,
                                       kbf, wkb, b_k, kp,
                                       wvb, vbf, b_v, vT);

    // attention: 2-pass online softmax; writes attn fp32 + z bf16
    attn_kernel<<<BATCH * NHEAD * (SEQ / 16), 256, 0, stream>>>(qp, kp, vT, zbf, attn_out);

    // output projection: z_out = z @ Wo^T + b_o (fp32 out)
    dim3 g1(D_MODEL / 64, BS_TOK / 128);       // (16, 32)
    gemm_bt<false, false><<<g1, 256, 0, stream>>>(zbf, wob, b_o, z_out, BS_TOK, D_MODEL, D_MODEL);
}

// Round 5
// 816.366 us; speedup vs baseline: 1.1768x; 1.1768x over previous
//
#include <hip/hip_runtime.h>
#include <hip/hip_bf16.h>
#include <stdint.h>

#define D_MODEL 1024
#define NHEAD   16
#define HDIM    64
#define BATCH   2
#define SEQ     2048
#define BS_TOK  (BATCH*SEQ)   // 4096 tokens

using bf16 = __hip_bfloat16;
typedef __attribute__((ext_vector_type(8))) short frag8;   // 8 bf16 = 4 VGPRs (A/B operand)
typedef __attribute__((ext_vector_type(4))) float facc4;   // 4 fp32 accumulator

// ---------------------------------------------------------------- async 16B global->LDS
__device__ __forceinline__ void gld_lds16(const void* g, void* l) {
    __builtin_amdgcn_global_load_lds(
        reinterpret_cast<const __attribute__((address_space(1))) uint32_t*>(
            reinterpret_cast<uintptr_t>(g)),
        reinterpret_cast<__attribute__((address_space(3))) uint32_t*>(
            reinterpret_cast<uintptr_t>(l)),
        16, 0, 0);
}

// ---------------------------------------------------------------- cvt fp32->bf16: all 7 tensors, one launch
__global__ __launch_bounds__(256) void cvt_all(const float* __restrict__ q, const float* __restrict__ k,
                                               const float* __restrict__ v, const float* __restrict__ wq,
                                               const float* __restrict__ wk, const float* __restrict__ wv,
                                               const float* __restrict__ wo,
                                               ushort* __restrict__ dq, ushort* __restrict__ dk,
                                               ushort* __restrict__ dv, ushort* __restrict__ dwq,
                                               ushort* __restrict__ dwk, ushort* __restrict__ dwv,
                                               ushort* __restrict__ dwo,
                                               int nbt, int n4t, int nbw, int n4w) {
    int blk = blockIdx.x;
    const float4* s; ushort4* d; int i, n4;
    if (blk < 3 * nbt) {
        int t = blk / nbt;
        i = (blk - t * nbt) * 256 + threadIdx.x; n4 = n4t;
        s = (const float4*)(t == 0 ? q : t == 1 ? k : v);
        d = (ushort4*)(t == 0 ? dq : t == 1 ? dk : dv);
    } else {
        blk -= 3 * nbt;
        int t = blk / nbw;
        i = (blk - t * nbw) * 256 + threadIdx.x; n4 = n4w;
        s = (const float4*)(t == 0 ? wq : t == 1 ? wk : t == 2 ? wv : wo);
        d = (ushort4*)(t == 0 ? dwq : t == 1 ? dwk : t == 2 ? dwv : dwo);
    }
    if (i >= n4) return;
    float4 vv = s[i];
    bf16 a = __float2bfloat16(vv.x), b = __float2bfloat16(vv.y),
         c = __float2bfloat16(vv.z), e = __float2bfloat16(vv.w);
    ushort4 u;
    __builtin_memcpy(&u.x, &a, 2);
    __builtin_memcpy(&u.y, &b, 2);
    __builtin_memcpy(&u.z, &c, 2);
    __builtin_memcpy(&u.w, &e, 2);
    d[i] = u;
}

// ---------------------------------------------------------------- GEMM core: C = A(MxK)*Bt(NxK)^T + bias
// 128x64 tile / 256 threads (4 waves 2x2), BK=64, 2-phase LDS double-buffer,
// global_load_lds width-16 with PRE-SWIZZLED global source (both-sides rule):
// stored[row][c8] = global[row][c8 ^ (row&7)], reads XOR the same way.
// C/D layout (verified gfx950): col = lane&15, row = (lane>>4)*4 + reg.
template<bool OUT_BF16, bool ROW_BIAS>
__device__ __forceinline__ void gemm_core(bf16* AsBuf, bf16* BsBuf,
                                          const bf16* __restrict__ A,
                                          const bf16* __restrict__ Bt,
                                          const float* __restrict__ bias,
                                          void* __restrict__ Cout,
                                          int M, int N, int K, int bx, int by) {
    const int tid  = threadIdx.x;
    const int lane = tid & 63, wave = tid >> 6;
    const int wm = wave >> 1, wn = wave & 1;
    const int L15 = lane & 15, quad = lane >> 4;
    const int m0 = by * 128, n0 = bx * 64;
    const int ar  = tid >> 3;                       // 0..31: row-sub within a 32-row group
    const int acS = ((tid & 7) ^ (ar & 7)) * 8;     // pre-swizzled k-chunk (elems)

    const bf16* Agl[4];
    const bf16* Bgl[2];
#pragma unroll
    for (int q = 0; q < 4; q++) Agl[q] = A + (size_t)(m0 + q * 32 + ar) * K + acS;
#pragma unroll
    for (int q = 0; q < 2; q++) Bgl[q] = Bt + (size_t)(n0 + q * 32 + ar) * K + acS;

    const facc4 zero4 = {0.f, 0.f, 0.f, 0.f};
    facc4 acc[4][2];
#pragma unroll
    for (int mt = 0; mt < 4; mt++) { acc[mt][0] = zero4; acc[mt][1] = zero4; }

#define G_STAGE(BUF, KO) do {                                                   \
        _Pragma("unroll")                                                       \
        for (int q = 0; q < 4; q++)                                             \
            gld_lds16(Agl[q] + (KO), AsBuf + (BUF) * 8192 + q * 2048 + wave * 512); \
        _Pragma("unroll")                                                       \
        for (int q = 0; q < 2; q++)                                             \
            gld_lds16(Bgl[q] + (KO), BsBuf + (BUF) * 4096 + q * 2048 + wave * 512); \
    } while (0)

#define G_COMPUTE(BUF) do {                                                     \
        const bf16* Ab = AsBuf + (BUF) * 8192;                                  \
        const bf16* Bb = BsBuf + (BUF) * 4096;                                  \
        _Pragma("unroll")                                                       \
        for (int h = 0; h < 2; h++) {                                           \
            frag8 af[4], bfr[2];                                                \
            _Pragma("unroll")                                                   \
            for (int mt = 0; mt < 4; mt++) {                                    \
                int row = wm * 64 + mt * 16 + L15;                              \
                int c8 = (h * 4 + quad) ^ (row & 7);                            \
                af[mt] = *(const frag8*)(Ab + row * 64 + c8 * 8);               \
            }                                                                   \
            _Pragma("unroll")                                                   \
            for (int nt = 0; nt < 2; nt++) {                                    \
                int row = wn * 32 + nt * 16 + L15;                              \
                int c8 = (h * 4 + quad) ^ (row & 7);                            \
                bfr[nt] = *(const frag8*)(Bb + row * 64 + c8 * 8);              \
            }                                                                   \
            _Pragma("unroll")                                                   \
            for (int mt = 0; mt < 4; mt++)                                      \
                _Pragma("unroll")                                               \
                for (int nt = 0; nt < 2; nt++)                                  \
                    acc[mt][nt] = __builtin_amdgcn_mfma_f32_16x16x32_bf16(af[mt], bfr[nt], acc[mt][nt], 0, 0, 0); \
        }                                                                       \
    } while (0)

    G_STAGE(0, 0);
    __syncthreads();
    int cur = 0;
    for (int k0 = 64; k0 < K; k0 += 64) {
        G_STAGE(cur ^ 1, k0);    // next tile's loads issue under current compute
        G_COMPUTE(cur);
        __syncthreads();         // drains next-stage + fences LDS reuse
        cur ^= 1;
    }
    G_COMPUTE(cur);

#pragma unroll
    for (int mt = 0; mt < 4; mt++)
#pragma unroll
        for (int nt = 0; nt < 2; nt++)
#pragma unroll
            for (int r = 0; r < 4; r++) {
                int row = m0 + wm * 64 + mt * 16 + quad * 4 + r;
                int col = n0 + wn * 32 + nt * 16 + L15;
                float v = acc[mt][nt][r] + (ROW_BIAS ? bias[row] : bias[col]);
                if (OUT_BF16) ((bf16*)Cout)[(size_t)row * N + col] = __float2bfloat16(v);
                else          ((float*)Cout)[(size_t)row * N + col] = v;
            }
#undef G_STAGE
#undef G_COMPUTE
}

// All three projection GEMMs in ONE launch: 1536 blocks = 6/CU.
__global__ __launch_bounds__(256) void proj_all(const bf16* __restrict__ qA, const bf16* __restrict__ Wq,
                                                const float* __restrict__ bq, bf16* __restrict__ qO,
                                                const bf16* __restrict__ kA, const bf16* __restrict__ Wk,
                                                const float* __restrict__ bk, bf16* __restrict__ kO,
                                                const bf16* __restrict__ Wv, const bf16* __restrict__ vA,
                                                const float* __restrict__ bv, bf16* __restrict__ vO) {
    __shared__ bf16 As[2 * 8192];   // 32 KB
    __shared__ bf16 Bs[2 * 4096];   // 16 KB
    int id = blockIdx.x;
    if (id < 512) {
        gemm_core<true, false>(As, Bs, qA, Wq, bq, qO, BS_TOK, D_MODEL, D_MODEL, id & 15, id >> 4);
    } else if (id < 1024) {
        id -= 512;
        gemm_core<true, false>(As, Bs, kA, Wk, bk, kO, BS_TOK, D_MODEL, D_MODEL, id & 15, id >> 4);
    } else {
        id -= 1024;   // vT = Wv @ v^T (role-swapped, row bias): grid (64, 8)
        gemm_core<true, true>(As, Bs, Wv, vA, bv, vO, D_MODEL, BS_TOK, D_MODEL, id & 63, id >> 6);
    }
}

template<bool OUT_BF16, bool ROW_BIAS>
__global__ __launch_bounds__(256) void gemm_bt(const bf16* __restrict__ A,
                                               const bf16* __restrict__ Bt,
                                               const float* __restrict__ bias,
                                               void* __restrict__ Cout,
                                               int M, int N, int K) {
    __shared__ bf16 As[2 * 8192];
    __shared__ bf16 Bs[2 * 4096];
    gemm_core<OUT_BF16, ROW_BIAS>(As, Bs, A, Bt, bias, Cout, M, N, K, blockIdx.x, blockIdx.y);
}

// ---------------------------------------------------------------- attention
// One block per (b, h, 32-row Q strip). 4 waves, 2 sub-strips of 16 rows that
// SHARE every K fragment (2 MFMA chains per load: halves K traffic, doubles
// MFMA ILP). Two-pass softmax:
//   pass 1: QK^T + exp -> row sums (no P storage).
//   pass 2: per 512-key chunk: recompute scores, write normalized attn fp32
//           straight from regs (plain stores -> L2 write-combines; verified
//           round 4: WRITE_SIZE stays at the mandatory 532 MB), stage bf16 P
//           in a 32 KB swizzled LDS tile, one __syncthreads, PV, one more.
// Single-buffered, low-VGPR regime (round 4's 128-VGPR dbuf regressed).
// T1 XCD-chunked block swizzle keeps each (b,h)'s K/V slice in one XCD L2.
__device__ __forceinline__ int pidx2(int row, int col) {
    int chunk = col >> 3;
    return row * 512 + (((chunk ^ (row & 7)) << 3) | (col & 7));
}

__global__ __launch_bounds__(256, 4) void attn_kernel(const bf16* __restrict__ qp,
                                                      const bf16* __restrict__ kp,
                                                      const bf16* __restrict__ vT,
                                                      bf16* __restrict__ zbuf,
                                                      float* __restrict__ attn_out) {
    __shared__ bf16 ptile[32 * 512];    // 32 KB swizzled P chunk (32 rows x 512 cols)
    __shared__ float sred[4][32];
    __shared__ float sinv[32];
    const int bid0 = blockIdx.x;
    const int bid = (bid0 & 7) * 256 + (bid0 >> 3);   // bijective XCD chunking (2048 = 8*256)
    const int strip = bid & 63, bh = bid >> 6;
    const int b = bh >> 4, h = bh & 15;
    const int i0 = strip * 32;
    const int tid = threadIdx.x, lane = tid & 63, wave = tid >> 6;
    const int L15 = lane & 15, quad = lane >> 4;
    const float scale = 0.125f;  // 1/sqrt(64)

    // Q fragments for both 16-row sub-strips: A[m=lane&15][k=quad*8+j]
    frag8 aq[2][2];
#pragma unroll
    for (int s = 0; s < 2; s++) {
        size_t base = (size_t)(b * SEQ + i0 + s * 16 + L15) * D_MODEL + h * HDIM + quad * 8;
        aq[s][0] = *(const frag8*)(qp + base);
        aq[s][1] = *(const frag8*)(qp + base + 32);
    }
    const facc4 zero4 = {0.f, 0.f, 0.f, 0.f};

    // ---- pass 1: row sums of exp(scores); |s| small: no max-subtraction needed
    float sums[2][4] = {{0.f, 0.f, 0.f, 0.f}, {0.f, 0.f, 0.f, 0.f}};
    for (int tt = 0; tt < 32; tt++) {
        int j0 = wave * 512 + tt * 16;
        size_t kb = (size_t)(b * SEQ + j0 + L15) * D_MODEL + h * HDIM + quad * 8;
        frag8 kf0 = *(const frag8*)(kp + kb);
        frag8 kf1 = *(const frag8*)(kp + kb + 32);
        facc4 a0 = zero4, a1 = zero4;
        a0 = __builtin_amdgcn_mfma_f32_16x16x32_bf16(aq[0][0], kf0, a0, 0, 0, 0);
        a1 = __builtin_amdgcn_mfma_f32_16x16x32_bf16(aq[1][0], kf0, a1, 0, 0, 0);
        a0 = __builtin_amdgcn_mfma_f32_16x16x32_bf16(aq[0][1], kf1, a0, 0, 0, 0);
        a1 = __builtin_amdgcn_mfma_f32_16x16x32_bf16(aq[1][1], kf1, a1, 0, 0, 0);
#pragma unroll
        for (int r = 0; r < 4; r++) {
            sums[0][r] += __expf(a0[r] * scale);
            sums[1][r] += __expf(a1[r] * scale);
        }
    }
#pragma unroll
    for (int m = 1; m <= 8; m <<= 1)
#pragma unroll
        for (int s = 0; s < 2; s++)
#pragma unroll
            for (int r = 0; r < 4; r++) sums[s][r] += __shfl_xor(sums[s][r], m, 64);
    if (L15 == 0) {
#pragma unroll
        for (int s = 0; s < 2; s++)
#pragma unroll
            for (int r = 0; r < 4; r++) sred[wave][s * 16 + quad * 4 + r] = sums[s][r];
    }
    __syncthreads();
    if (tid < 32) sinv[tid] = 1.0f / (sred[0][tid] + sred[1][tid] + sred[2][tid] + sred[3][tid]);
    __syncthreads();

    float invr[2][4];
#pragma unroll
    for (int s = 0; s < 2; s++)
#pragma unroll
        for (int r = 0; r < 4; r++) invr[s][r] = sinv[s * 16 + quad * 4 + r];

    // ---- pass 2: per-chunk recompute -> reg-direct attn stores + P stage -> PV
    facc4 zacc[2] = {zero4, zero4};
    const bf16* vrow = vT + (size_t)(h * HDIM + wave * 16 + L15) * BS_TOK + b * SEQ;
    const size_t obase = ((size_t)bh * SEQ + i0) * SEQ;

    for (int c = 0; c < 4; c++) {
#pragma unroll 2
        for (int tt = 0; tt < 8; tt++) {
            int jrel = wave * 128 + tt * 16;        // col within chunk
            int j0 = c * 512 + jrel;                // global key col base
            size_t kb = (size_t)(b * SEQ + j0 + L15) * D_MODEL + h * HDIM + quad * 8;
            frag8 kf0 = *(const frag8*)(kp + kb);
            frag8 kf1 = *(const frag8*)(kp + kb + 32);
            facc4 a0 = zero4, a1 = zero4;
            a0 = __builtin_amdgcn_mfma_f32_16x16x32_bf16(aq[0][0], kf0, a0, 0, 0, 0);
            a1 = __builtin_amdgcn_mfma_f32_16x16x32_bf16(aq[1][0], kf0, a1, 0, 0, 0);
            a0 = __builtin_amdgcn_mfma_f32_16x16x32_bf16(aq[0][1], kf1, a0, 0, 0, 0);
            a1 = __builtin_amdgcn_mfma_f32_16x16x32_bf16(aq[1][1], kf1, a1, 0, 0, 0);
            int colw = jrel + L15;
#pragma unroll
            for (int r = 0; r < 4; r++) {
                int row0 = quad * 4 + r;
                float p0 = __expf(a0[r] * scale) * invr[0][r];
                float p1 = __expf(a1[r] * scale) * invr[1][r];
                attn_out[obase + (size_t)row0 * SEQ + j0 + L15] = p0;
                attn_out[obase + (size_t)(row0 + 16) * SEQ + j0 + L15] = p1;
                ptile[pidx2(row0, colw)] = __float2bfloat16(p0);
                ptile[pidx2(row0 + 16, colw)] = __float2bfloat16(p1);
            }
        }
        __syncthreads();
        // PV over this chunk: A = P[q][k] (both sub-strips), B = vT[d=wave*16+L15][k]
#pragma unroll 4
        for (int k0 = 0; k0 < 512; k0 += 32) {
            int sw = ((((k0 >> 3) + quad) ^ (L15 & 7)) << 3);
            frag8 pa0 = *(const frag8*)&ptile[L15 * 512 + sw];
            frag8 pa1 = *(const frag8*)&ptile[(L15 + 16) * 512 + sw];
            frag8 vb = *(const frag8*)(vrow + c * 512 + k0 + quad * 8);
            zacc[0] = __builtin_amdgcn_mfma_f32_16x16x32_bf16(pa0, vb, zacc[0], 0, 0, 0);
            zacc[1] = __builtin_amdgcn_mfma_f32_16x16x32_bf16(pa1, vb, zacc[1], 0, 0, 0);
        }
        __syncthreads();
    }
    // z write: z[q][d=wave*16+L15], already normalized (P was normalized)
#pragma unroll
    for (int s = 0; s < 2; s++)
#pragma unroll
        for (int r = 0; r < 4; r++) {
            size_t row = (size_t)(b * SEQ + i0 + s * 16 + quad * 4 + r);
            zbuf[row * D_MODEL + h * HDIM + wave * 16 + L15] = __float2bfloat16(zacc[s][r]);
        }
}

// ---------------------------------------------------------------- launch
extern "C" void kernel_launch(void* const* d_in, const int* in_sizes, int n_in,
                              void* d_out, int out_size, void* d_ws, size_t ws_size,
                              hipStream_t stream) {
    const float* q   = (const float*)d_in[0];
    const float* k   = (const float*)d_in[1];
    const float* v   = (const float*)d_in[2];
    const float* w_q = (const float*)d_in[3];
    const float* b_q = (const float*)d_in[4];
    const float* w_k = (const float*)d_in[5];
    const float* b_k = (const float*)d_in[6];
    const float* w_v = (const float*)d_in[7];
    const float* b_v = (const float*)d_in[8];
    const float* w_o = (const float*)d_in[9];
    const float* b_o = (const float*)d_in[10];

    char* ws = (char*)d_ws;
    const size_t TOK = (size_t)BS_TOK * D_MODEL;      // 4.19M elems
    const size_t WM  = (size_t)D_MODEL * D_MODEL;     // 1.05M elems
    bf16* qbf  = (bf16*)(ws);                          // 8 MB
    bf16* kbf  = (bf16*)(ws + 8388608);
    bf16* vbf  = (bf16*)(ws + 16777216);
    bf16* wqb  = (bf16*)(ws + 25165824);               // 2 MB each
    bf16* wkb  = (bf16*)(ws + 27262976);
    bf16* wvb  = (bf16*)(ws + 29360128);
    bf16* wob  = (bf16*)(ws + 31457280);
    bf16* qp   = (bf16*)(ws + 33554432);               // 8 MB
    bf16* kp   = (bf16*)(ws + 41943040);
    bf16* vT   = (bf16*)(ws + 50331648);               // V^T per feature row
    bf16* zbf  = (bf16*)(ws + 58720256);

    float* z_out    = (float*)d_out;
    float* attn_out = (float*)d_out + (size_t)BATCH * SEQ * D_MODEL;  // +4194304

    // fp32 -> bf16: all 7 tensors, one launch
    int n4t = (int)(TOK / 4), n4w = (int)(WM / 4);
    int nbt = (n4t + 255) / 256, nbw = (n4w + 255) / 256;
    cvt_all<<<3 * nbt + 4 * nbw, 256, 0, stream>>>(q, k, v, w_q, w_k, w_v, w_o,
                                                   (ushort*)qbf, (ushort*)kbf, (ushort*)vbf,
                                                   (ushort*)wqb, (ushort*)wkb, (ushort*)wvb,
                                                   (ushort*)wob, nbt, n4t, nbw, n4w);

    // all three projections in one launch (Q, K, and role-swapped V^T)
    proj_all<<<1536, 256, 0, stream>>>(qbf, wqb, b_q, qp,
                                       kbf, wkb, b_k, kp,
                                       wvb, vbf, b_v, vT);

    // attention: 2-pass softmax, 32 Q-rows/block; writes attn fp32 + z bf16
    attn_kernel<<<BATCH * NHEAD * (SEQ / 32), 256, 0, stream>>>(qp, kp, vT, zbf, attn_out);

    // output projection: z_out = z @ Wo^T + b_o (fp32 out)
    dim3 g1(D_MODEL / 64, BS_TOK / 128);       // (16, 32)
    gemm_bt<false, false><<<g1, 256, 0, stream>>>(zbf, wob, b_o, z_out, BS_TOK, D_MODEL, D_MODEL);
}